// Round 2
// baseline (206.408 us; speedup 1.0000x reference)
//
#include <hip/hip_runtime.h>
#include <stdint.h>

#define NR 8192
#define DD 128

typedef __attribute__((ext_vector_type(8))) short bf16x8;
typedef __attribute__((ext_vector_type(4))) float f32x4;

#ifdef __has_builtin
#if __has_builtin(__builtin_amdgcn_exp2f)
#define EXP2F __builtin_amdgcn_exp2f
#endif
#endif
#ifndef EXP2F
#define EXP2F exp2f
#endif

// exp(10*x) == exp2(x * 10/ln2).  We fold the 10/ln2 into the stored bf16
// values: nb = round_bf16( sqrt(10/ln2) * normalized ), so every pairwise
// product (MFMA dot, p0 elementwise, diag) is already the exp2 argument.
#define K10_LOG2E 14.4269504088896340f
#define SQK 3.79828255f   // sqrt(10/ln2)

__device__ __forceinline__ uint16_t f2bf_rne(float f) {
  uint32_t u = __float_as_uint(f);
  u += 0x7FFFu + ((u >> 16) & 1u);
  return (uint16_t)(u >> 16);
}
__device__ __forceinline__ float bf2f(uint16_t h) {
  return __uint_as_float(((uint32_t)h) << 16);
}

// ---------------------------------------------------------------------------
// K1: row L2-normalize (fp32 math), emit bf16 copies scaled by SQK, plus
// diag = sum(stored^2) (so exp2(diag) is exactly the MFMA diagonal term).
// Also zeroes the 6 row-sum arrays and d_out. One wave per row.
// ---------------------------------------------------------------------------
__global__ __launch_bounds__(256) void k_normalize(
    const float* __restrict__ u1, const float* __restrict__ u2,
    const float* __restrict__ i1, const float* __restrict__ i2,
    uint16_t* __restrict__ nb, float* __restrict__ diag,
    float* __restrict__ sums, float* __restrict__ out)
{
  int tid = threadIdx.x;
  int gid = blockIdx.x * 256 + tid;
  if (gid < 6 * NR) sums[gid] = 0.0f;
  if (gid == 0) out[0] = 0.0f;

  int w = tid >> 6, lane = tid & 63;
  int rowId = blockIdx.x * 4 + w;            // 0..32767
  int mi = rowId >> 13, r = rowId & (NR - 1);
  const float* src = (mi == 0) ? u1 : (mi == 1) ? u2 : (mi == 2) ? i1 : i2;
  const float2 v = *(const float2*)(src + (size_t)r * DD + lane * 2);
  float ss = v.x * v.x + v.y * v.y;
#pragma unroll
  for (int off = 32; off >= 1; off >>= 1) ss += __shfl_xor(ss, off, 64);
  float sc = SQK / fmaxf(sqrtf(ss), 1e-12f);
  uint16_t b0 = f2bf_rne(v.x * sc);
  uint16_t b1 = f2bf_rne(v.y * sc);
  uint16_t* dst = nb + (size_t)mi * NR * DD + (size_t)r * DD + lane * 2;
  *(uint32_t*)dst = (uint32_t)b0 | ((uint32_t)b1 << 16);
  float f0 = bf2f(b0), f1 = bf2f(b1);
  float dd = f0 * f0 + f1 * f1;
#pragma unroll
  for (int off = 32; off >= 1; off >>= 1) dd += __shfl_xor(dd, off, 64);
  if (lane == 0) diag[rowId] = dd;
}

// ---------------------------------------------------------------------------
// K2: Gram row-sums, NO LDS.  All 4 bf16 matrices = 8 MB, each job's B is
// 2 MB -> fully L2-resident (4 MB/XCD).  B fragments are read straight from
// global (L1/L2 hits), zero barriers, so MFMA / trans / VMEM pipes overlap
// freely across the 12 resident waves per CU.
// Block: 4 waves x 64 rows (MR=4) = 256 rows; 4 col-chunks of 2048 cols.
// grid = 6*32*4 = 768 blocks (3/CU), XCD-chunked swizzle (768 % 8 == 0).
// ---------------------------------------------------------------------------
__global__ __launch_bounds__(256, 3) void k_gram(
    const uint16_t* __restrict__ nb, float* __restrict__ sums)
{
  // bijective XCD-chunk swizzle: XCD k gets contiguous ids [k*96,(k+1)*96)
  int bid = (blockIdx.x & 7) * 96 + (blockIdx.x >> 3);
  int job = bid >> 7;          // 128 blocks per job
  int rem = bid & 127;
  int rb = rem >> 2;           // row-block 0..31 (256 rows each)
  int cs = rem & 3;            // col-chunk 0..3  (2048 cols each)
  const int ja[6] = {0, 0, 1, 2, 2, 3};
  const int jb[6] = {1, 0, 1, 3, 2, 3};
  const uint16_t* A = nb + (size_t)ja[job] * NR * DD;
  const uint16_t* B = nb + (size_t)jb[job] * NR * DD;
  float* out = sums + job * NR;

  int tid = threadIdx.x, w = tid >> 6, lane = tid & 63;
  int l15 = lane & 15, lg = lane >> 4;
  int rowBase = rb * 256 + w * 64;

  // A fragments in registers: lane holds row (l15), k = ks*32 + lg*8 .. +8
  bf16x8 af[4][4];
#pragma unroll
  for (int m = 0; m < 4; ++m) {
    const uint16_t* ap = A + (size_t)(rowBase + m * 16 + l15) * DD + lg * 8;
#pragma unroll
    for (int ks = 0; ks < 4; ++ks)
      af[m][ks] = *(const bf16x8*)(ap + ks * 32);
  }

  float racc[4][4];
#pragma unroll
  for (int m = 0; m < 4; ++m)
#pragma unroll
    for (int j = 0; j < 4; ++j) racc[m][j] = 0.0f;

  int jstart = cs * 2048;

  for (int jt = 0; jt < 32; ++jt) {
    const uint16_t* tb = B + (size_t)(jstart + jt * 64) * DD;
    // 16 direct loads (L1/L2-hit): B rows c*16+l15, k-chunk ks*32+lg*8
    bf16x8 bf[4][4];
#pragma unroll
    for (int c = 0; c < 4; ++c) {
      const uint16_t* bp = tb + (size_t)(c * 16 + l15) * DD + lg * 8;
#pragma unroll
      for (int ks = 0; ks < 4; ++ks)
        bf[c][ks] = *(const bf16x8*)(bp + ks * 32);
    }
#pragma unroll
    for (int c = 0; c < 4; ++c) {
#pragma unroll
      for (int m = 0; m < 4; ++m) {
        f32x4 acc = {0.0f, 0.0f, 0.0f, 0.0f};
#pragma unroll
        for (int ks = 0; ks < 4; ++ks)
          acc = __builtin_amdgcn_mfma_f32_16x16x32_bf16(af[m][ks], bf[c][ks], acc, 0, 0, 0);
        // C/D layout: col = lane&15, row = (lane>>4)*4 + j  [m89-verified]
        // inputs pre-scaled: acc IS the exp2 argument
#pragma unroll
        for (int j = 0; j < 4; ++j)
          racc[m][j] += EXP2F(acc[j]);
      }
    }
  }

  // reduce over the 16 lanes (same lg group) holding different cols
#pragma unroll
  for (int off = 1; off < 16; off <<= 1)
#pragma unroll
    for (int m = 0; m < 4; ++m)
#pragma unroll
      for (int j = 0; j < 4; ++j)
        racc[m][j] += __shfl_xor(racc[m][j], off, 64);

  if (l15 == 0) {
#pragma unroll
    for (int m = 0; m < 4; ++m)
#pragma unroll
      for (int j = 0; j < 4; ++j)
        atomicAdd(&out[rowBase + m * 16 + lg * 4 + j], racc[m][j]);
  }
}

// ---------------------------------------------------------------------------
// K3: finalize.  16 rows per wave, one atomic per BLOCK (256 total, was 4096
// same-address atomics = ~50us serialized).
// loss += log(s12+s11+p0) + log(s12+s22+p0) - 2*log(p0);  out = loss/4.
// ---------------------------------------------------------------------------
__global__ __launch_bounds__(256) void k_finalize(
    const uint16_t* __restrict__ nb, const float* __restrict__ diag,
    const float* __restrict__ sums, float* __restrict__ out)
{
  __shared__ float part[4];
  int tid = threadIdx.x, w = tid >> 6, lane = tid & 63;
  int waveId = blockIdx.x * 4 + w;        // 0..1023
  float local = 0.0f;

  for (int i = 0; i < 16; ++i) {
    int rowId = waveId * 16 + i;          // 0..16383
    int p = rowId >> 13, r = rowId & (NR - 1);
    const uint16_t* n1 = nb + (size_t)(2 * p) * NR * DD + (size_t)r * DD;
    const uint16_t* n2 = n1 + (size_t)NR * DD;
    uint32_t a = *(const uint32_t*)(n1 + lane * 2);
    uint32_t b = *(const uint32_t*)(n2 + lane * 2);
    float a0 = bf2f((uint16_t)(a & 0xFFFFu)), a1 = bf2f((uint16_t)(a >> 16));
    float b0 = bf2f((uint16_t)(b & 0xFFFFu)), b1 = bf2f((uint16_t)(b >> 16));
    // values pre-scaled by SQK: product is already the exp2 argument
    float p0 = EXP2F(a0 * b0) + EXP2F(a1 * b1);
#pragma unroll
    for (int off = 32; off >= 1; off >>= 1) p0 += __shfl_xor(p0, off, 64);

    if (lane == 0) {
      const float* s12v = sums + (3 * p) * NR;
      const float* s11v = sums + (3 * p + 1) * NR;
      const float* s22v = sums + (3 * p + 2) * NR;
      float e1 = EXP2F(diag[(2 * p) * NR + r]);
      float e2 = EXP2F(diag[(2 * p + 1) * NR + r]);
      float s12 = s12v[r];
      float S1 = s12 + (s11v[r] - e1) + p0;
      float S2 = s12 + (s22v[r] - e2) + p0;
      local += logf(S1) + logf(S2) - 2.0f * logf(p0);
    }
  }
  if (lane == 0) part[w] = local;
  __syncthreads();
  if (tid == 0) {
    float t = part[0] + part[1] + part[2] + part[3];
    atomicAdd(out, 0.25f * t);
  }
}

// ---------------------------------------------------------------------------
extern "C" void kernel_launch(void* const* d_in, const int* in_sizes, int n_in,
                              void* d_out, int out_size, void* d_ws, size_t ws_size,
                              hipStream_t stream) {
  const float* u1 = (const float*)d_in[0];
  const float* u2 = (const float*)d_in[1];
  const float* i1 = (const float*)d_in[2];
  const float* i2 = (const float*)d_in[3];

  // ws layout: 4 bf16 matrices (8 MB) | diag[4][NR] f32 | sums[6][NR] f32
  uint16_t* nb = (uint16_t*)d_ws;
  float* diag = (float*)((char*)d_ws + (size_t)4 * NR * DD * sizeof(uint16_t));
  float* sums = diag + 4 * NR;
  float* out = (float*)d_out;

  k_normalize<<<NR * 4 / 4, 256, 0, stream>>>(u1, u2, i1, i2, nb, diag, sums, out);
  k_gram<<<768, 256, 0, stream>>>(nb, sums);
  k_finalize<<<256, 256, 0, stream>>>(nb, diag, sums, out);
}

// Round 3
// 125.036 us; speedup vs baseline: 1.6508x; 1.6508x over previous
//
#include <hip/hip_runtime.h>
#include <stdint.h>

#define NR 8192
#define DD 128

typedef __attribute__((ext_vector_type(8))) short bf16x8;
typedef __attribute__((ext_vector_type(4))) float f32x4;

#ifdef __has_builtin
#if __has_builtin(__builtin_amdgcn_exp2f)
#define EXP2F __builtin_amdgcn_exp2f
#endif
#endif
#ifndef EXP2F
#define EXP2F exp2f
#endif

// exp(10*x) == exp2(x * 10/ln2).  The 10/ln2 is folded into the stored bf16:
// nb = round_bf16( sqrt(10/ln2) * normalized ), so every pairwise product
// (MFMA dot, p0 elementwise, diag) is already the exp2 argument.
#define SQK 3.79828255f   // sqrt(10/ln2)

__device__ __forceinline__ uint16_t f2bf_rne(float f) {
  uint32_t u = __float_as_uint(f);
  u += 0x7FFFu + ((u >> 16) & 1u);
  return (uint16_t)(u >> 16);
}
__device__ __forceinline__ float bf2f(uint16_t h) {
  return __uint_as_float(((uint32_t)h) << 16);
}

// ---------------------------------------------------------------------------
// K1: row L2-normalize (fp32 math), emit bf16 copies scaled by SQK, plus
// diag = sum(stored^2). Also zeroes the 6 row-sum arrays and d_out.
// ---------------------------------------------------------------------------
__global__ __launch_bounds__(256) void k_normalize(
    const float* __restrict__ u1, const float* __restrict__ u2,
    const float* __restrict__ i1, const float* __restrict__ i2,
    uint16_t* __restrict__ nb, float* __restrict__ diag,
    float* __restrict__ sums, float* __restrict__ out)
{
  int tid = threadIdx.x;
  int gid = blockIdx.x * 256 + tid;
  if (gid < 6 * NR) sums[gid] = 0.0f;
  if (gid == 0) out[0] = 0.0f;

  int w = tid >> 6, lane = tid & 63;
  int rowId = blockIdx.x * 4 + w;            // 0..32767
  int mi = rowId >> 13, r = rowId & (NR - 1);
  const float* src = (mi == 0) ? u1 : (mi == 1) ? u2 : (mi == 2) ? i1 : i2;
  const float2 v = *(const float2*)(src + (size_t)r * DD + lane * 2);
  float ss = v.x * v.x + v.y * v.y;
#pragma unroll
  for (int off = 32; off >= 1; off >>= 1) ss += __shfl_xor(ss, off, 64);
  float sc = SQK / fmaxf(sqrtf(ss), 1e-12f);
  uint16_t b0 = f2bf_rne(v.x * sc);
  uint16_t b1 = f2bf_rne(v.y * sc);
  uint16_t* dst = nb + (size_t)mi * NR * DD + (size_t)r * DD + lane * 2;
  *(uint32_t*)dst = (uint32_t)b0 | ((uint32_t)b1 << 16);
  float f0 = bf2f(b0), f1 = bf2f(b1);
  float dd = f0 * f0 + f1 * f1;
#pragma unroll
  for (int off = 32; off >= 1; off >>= 1) dd += __shfl_xor(dd, off, 64);
  if (lane == 0) diag[rowId] = dd;
}

// ---------------------------------------------------------------------------
// K2: Gram row-sums, LDS-staged with T3 minimum-2-phase pipeline:
// double-buffered 2x16KB LDS, stage tile t+1 via global_load_lds BEFORE
// computing tile t, ONE __syncthreads per tile (its implicit vmcnt(0) drain
// is the staging sync).  Loads fly under the 64-MFMA + 64-exp compute phase.
// Block: 4 waves x 64 rows (MR=4) = 256 rows; 4 col-chunks of 2048 cols.
// grid = 6*32*4 = 768 blocks (3/CU), XCD-chunked bijective swizzle.
// ---------------------------------------------------------------------------
__global__ __launch_bounds__(256, 3) void k_gram(
    const uint16_t* __restrict__ nb, float* __restrict__ sums)
{
  __shared__ alignas(16) uint16_t ldsB[2][64 * DD];   // 2 x 16 KB

  // bijective XCD-chunk swizzle: XCD k gets contiguous ids [k*96,(k+1)*96)
  int bid = (blockIdx.x & 7) * 96 + (blockIdx.x >> 3);
  int job = bid >> 7;          // 128 blocks per job
  int rem = bid & 127;
  int rb = rem >> 2;           // row-block 0..31 (256 rows each)
  int cs = rem & 3;            // col-chunk 0..3  (2048 cols each)
  const int ja[6] = {0, 0, 1, 2, 2, 3};
  const int jb[6] = {1, 0, 1, 3, 2, 3};
  const uint16_t* A = nb + (size_t)ja[job] * NR * DD;
  const uint16_t* B = nb + (size_t)jb[job] * NR * DD;
  float* out = sums + job * NR;

  int tid = threadIdx.x, w = tid >> 6, lane = tid & 63;
  int l15 = lane & 15, lg = lane >> 4;
  int rowBase = rb * 256 + w * 64;

  const char* Bb = (const char*)B;
  char* buf0 = (char*)&ldsB[0][0];
  char* buf1 = (char*)&ldsB[1][0];
  int jstart = cs * 2048;

  // stage one 64-row B tile (16KB) into dst: linear LDS dest,
  // inverse-swizzled global source (rule #21)
#define STAGE(dst, jt)                                                        \
  {                                                                           \
    const char* tbase = Bb + (size_t)(jstart + (jt) * 64) * 256;              \
    _Pragma("unroll")                                                         \
    for (int it = 0; it < 4; ++it) {                                          \
      int dbase = w * 4096 + it * 1024;                                       \
      int doff = dbase + lane * 16;                                           \
      int soff = doff ^ (((doff >> 8) & 7) << 4);                             \
      __builtin_amdgcn_global_load_lds(                                       \
          (const __attribute__((address_space(1))) void*)(tbase + soff),      \
          (__attribute__((address_space(3))) void*)((dst) + dbase),           \
          16, 0, 0);                                                          \
    }                                                                         \
  }

  // prologue: stage tile 0; A-fragment loads fly under it
  STAGE(buf0, 0);

  bf16x8 af[4][4];
#pragma unroll
  for (int m = 0; m < 4; ++m) {
    const uint16_t* ap = A + (size_t)(rowBase + m * 16 + l15) * DD + lg * 8;
#pragma unroll
    for (int ks = 0; ks < 4; ++ks)
      af[m][ks] = *(const bf16x8*)(ap + ks * 32);
  }

  float racc[4][4];
#pragma unroll
  for (int m = 0; m < 4; ++m)
#pragma unroll
    for (int j = 0; j < 4; ++j) racc[m][j] = 0.0f;

  __syncthreads();   // tile 0 staged (implicit vmcnt(0) drain)

#define COMPUTE(bufc)                                                         \
  {                                                                           \
    _Pragma("unroll")                                                         \
    for (int c = 0; c < 4; ++c) {                                             \
      int r = c * 16 + l15;                                                   \
      int rbyte = r * 256;                                                    \
      int swz = (r & 7) << 4;                                                 \
      bf16x8 bfr[4];                                                          \
      _Pragma("unroll")                                                       \
      for (int ks = 0; ks < 4; ++ks) {                                        \
        int L = rbyte + ks * 64 + lg * 16;                                    \
        bfr[ks] = *(const bf16x8*)((bufc) + (L ^ swz));                       \
      }                                                                       \
      _Pragma("unroll")                                                       \
      for (int m = 0; m < 4; ++m) {                                           \
        f32x4 acc = {0.0f, 0.0f, 0.0f, 0.0f};                                 \
        _Pragma("unroll")                                                     \
        for (int ks = 0; ks < 4; ++ks)                                        \
          acc = __builtin_amdgcn_mfma_f32_16x16x32_bf16(af[m][ks], bfr[ks],   \
                                                        acc, 0, 0, 0);        \
        _Pragma("unroll")                                                     \
        for (int j = 0; j < 4; ++j)                                           \
          racc[m][j] += EXP2F(acc[j]);                                        \
      }                                                                       \
    }                                                                         \
  }

  // main loop: 2-phase pipeline, one barrier per tile
  for (int jt = 0; jt < 31; ++jt) {
    char* curb = (jt & 1) ? buf1 : buf0;
    char* nxtb = (jt & 1) ? buf0 : buf1;
    STAGE(nxtb, jt + 1);         // issue next-tile loads (stay in flight)
    COMPUTE(curb);               // ds_read + MFMA + exp2 cover the latency
    __syncthreads();             // drains vmcnt: next tile ready; cur reusable
  }
  COMPUTE(buf1);                 // tile 31 (no prefetch)

  // reduce over the 16 lanes (same lg group) holding different cols
#pragma unroll
  for (int off = 1; off < 16; off <<= 1)
#pragma unroll
    for (int m = 0; m < 4; ++m)
#pragma unroll
      for (int j = 0; j < 4; ++j)
        racc[m][j] += __shfl_xor(racc[m][j], off, 64);

  if (l15 == 0) {
#pragma unroll
    for (int m = 0; m < 4; ++m)
#pragma unroll
      for (int j = 0; j < 4; ++j)
        atomicAdd(&out[rowBase + m * 16 + lg * 4 + j], racc[m][j]);
  }
#undef STAGE
#undef COMPUTE
}

// ---------------------------------------------------------------------------
// K3: finalize.  16 rows per wave, one atomic per BLOCK (256 total).
// loss += log(s12+s11+p0) + log(s12+s22+p0) - 2*log(p0);  out = loss/4.
// ---------------------------------------------------------------------------
__global__ __launch_bounds__(256) void k_finalize(
    const uint16_t* __restrict__ nb, const float* __restrict__ diag,
    const float* __restrict__ sums, float* __restrict__ out)
{
  __shared__ float part[4];
  int tid = threadIdx.x, w = tid >> 6, lane = tid & 63;
  int waveId = blockIdx.x * 4 + w;        // 0..1023
  float local = 0.0f;

  for (int i = 0; i < 16; ++i) {
    int rowId = waveId * 16 + i;          // 0..16383
    int p = rowId >> 13, r = rowId & (NR - 1);
    const uint16_t* n1 = nb + (size_t)(2 * p) * NR * DD + (size_t)r * DD;
    const uint16_t* n2 = n1 + (size_t)NR * DD;
    uint32_t a = *(const uint32_t*)(n1 + lane * 2);
    uint32_t b = *(const uint32_t*)(n2 + lane * 2);
    float a0 = bf2f((uint16_t)(a & 0xFFFFu)), a1 = bf2f((uint16_t)(a >> 16));
    float b0 = bf2f((uint16_t)(b & 0xFFFFu)), b1 = bf2f((uint16_t)(b >> 16));
    // values pre-scaled by SQK: product is already the exp2 argument
    float p0 = EXP2F(a0 * b0) + EXP2F(a1 * b1);
#pragma unroll
    for (int off = 32; off >= 1; off >>= 1) p0 += __shfl_xor(p0, off, 64);

    if (lane == 0) {
      const float* s12v = sums + (3 * p) * NR;
      const float* s11v = sums + (3 * p + 1) * NR;
      const float* s22v = sums + (3 * p + 2) * NR;
      float e1 = EXP2F(diag[(2 * p) * NR + r]);
      float e2 = EXP2F(diag[(2 * p + 1) * NR + r]);
      float s12 = s12v[r];
      float S1 = s12 + (s11v[r] - e1) + p0;
      float S2 = s12 + (s22v[r] - e2) + p0;
      local += logf(S1) + logf(S2) - 2.0f * logf(p0);
    }
  }
  if (lane == 0) part[w] = local;
  __syncthreads();
  if (tid == 0) {
    float t = part[0] + part[1] + part[2] + part[3];
    atomicAdd(out, 0.25f * t);
  }
}

// ---------------------------------------------------------------------------
extern "C" void kernel_launch(void* const* d_in, const int* in_sizes, int n_in,
                              void* d_out, int out_size, void* d_ws, size_t ws_size,
                              hipStream_t stream) {
  const float* u1 = (const float*)d_in[0];
  const float* u2 = (const float*)d_in[1];
  const float* i1 = (const float*)d_in[2];
  const float* i2 = (const float*)d_in[3];

  // ws layout: 4 bf16 matrices (8 MB) | diag[4][NR] f32 | sums[6][NR] f32
  uint16_t* nb = (uint16_t*)d_ws;
  float* diag = (float*)((char*)d_ws + (size_t)4 * NR * DD * sizeof(uint16_t));
  float* sums = diag + 4 * NR;
  float* out = (float*)d_out;

  k_normalize<<<NR * 4 / 4, 256, 0, stream>>>(u1, u2, i1, i2, nb, diag, sums, out);
  k_gram<<<768, 256, 0, stream>>>(nb, sums);
  k_finalize<<<256, 256, 0, stream>>>(nb, diag, sums, out);
}